// Round 11
// baseline (101.920 us; speedup 1.0000x reference)
//
#include <hip/hip_runtime.h>
#include <hip/hip_bf16.h>
#include <math.h>

#define NN    87
#define NN2   (NN * NN)          // 7569
#define PW    92                 // E/D/X panel width in shorts (184 B rows)
#define PN    (96 * PW + 16)     // 8848 shorts per panel (incl zero tail)
#define WPH   104                // ws W-panel row stride (shorts)
#define WPANEL (96 * WPH)        // 9984 shorts
#define NT    256

#define WS_NEED (2 * WPANEL * 2) // 39936 B: just the two bf16 W panels

typedef __attribute__((ext_vector_type(8))) short bf16x8;
typedef __attribute__((ext_vector_type(4))) short bf16x4;
typedef __attribute__((ext_vector_type(4))) float f32x4;
typedef float f32x4u __attribute__((ext_vector_type(4), aligned(4)));

__device__ __forceinline__ short f2bf(float f) {
    __hip_bfloat16 h = __float2bfloat16(f);
    return *(short*)&h;
}
__device__ __forceinline__ float bf2f(short s) {
    union { unsigned u; float f; } v;
    v.u = ((unsigned)(unsigned short)s) << 16;
    return v.f;
}

// W (87x174 fp32) -> two zero-padded bf16 panels [96][104]
__global__ void prep(const float* __restrict__ W, short* __restrict__ wp) {
    int idx = (int)blockIdx.x * NT + (int)threadIdx.x;
    if (idx >= 2 * WPANEL) return;
    int p = idx / WPANEL, rem = idx - p * WPANEL;
    int r = rem / WPH, c = rem - r * WPH;
    short v = 0;
    if (r < NN && c < NN) v = f2bf(W[r * (2 * NN) + p * NN + c]);
    wp[idx] = v;
}

template <bool WS>
__device__ __forceinline__ bf16x8 wload(const short* __restrict__ wp,
                                        const float* __restrict__ gW,
                                        int panel, int jrow, int jcl, int k0, bool tailKs)
{
    if constexpr (WS) {
        return *(const bf16x8*)&wp[panel * WPANEL + jrow * WPH + k0];
    } else {
        float v[8];
        if (!tailKs) {
            f32x4u a  = *(const f32x4u*)(gW + jcl * (2 * NN) + panel * NN + k0);
            f32x4u b4 = *(const f32x4u*)(gW + jcl * (2 * NN) + panel * NN + k0 + 4);
            v[0] = a.x; v[1] = a.y; v[2] = a.z; v[3] = a.w;
            v[4] = b4.x; v[5] = b4.y; v[6] = b4.z; v[7] = b4.w;
        } else {
            #pragma unroll
            for (int q = 0; q < 8; ++q) {
                int k = k0 + q;
                v[q] = (k < NN) ? gW[jcl * (2 * NN) + panel * NN + k] : 0.f;
            }
        }
        bf16x8 o;
        #pragma unroll
        for (int q = 0; q < 8; ++q) o[q] = f2bf(v[q]);
        return o;
    }
}

template <bool WS>
__global__ __launch_bounds__(NT, 4)
void fused(const float* __restrict__ gx, const float* __restrict__ gevals,
           const float* __restrict__ gevecs, const float* __restrict__ dtime,
           const float* __restrict__ gW, const float* __restrict__ bias,
           const short* __restrict__ wp, float* __restrict__ out)
{
    // smem: sE [96][92] bf16 | sX [96][92] bf16 ; sD aliases sE after GEMM1;
    // sF [96][87] f32 (33408B) aliases both panels after GEMM2. Total ~35.8 KB.
    __shared__ __align__(16) short smem[2 * PN];
    short* const sE = smem;
    short* const sX = smem + PN;
    short* const sD = smem;
    float* const sF = (float*)smem;
    __shared__ float sLam[96];

    const int b    = (int)blockIdx.x;
    const int tid  = (int)threadIdx.x;
    const int lane = tid & 63;
    const int wave = tid >> 6;
    const int l15  = lane & 15;
    const int lk   = lane >> 4;
    const int i0   = (wave >> 1) * 48;
    const int j0   = (wave & 1) * 48;

    const float* __restrict__ Eb = gevecs + (size_t)b * NN2;
    const float* __restrict__ xb = gx     + (size_t)b * NN2;
    const short* wpp = WS ? wp : nullptr;

    if (tid < 96) sLam[tid] = (tid < NN) ? gevals[(size_t)b * NN + tid] : 3e38f;

    int ir[3], jr[3];
    float tr_[3];
    #pragma unroll
    for (int r = 0; r < 3; ++r) {
        ir[r] = i0 + 16 * r + l15;
        jr[r] = j0 + 16 * r + l15;
        tr_[r] = fmaxf(dtime[ir[r] < NN ? ir[r] : NN - 1], 1e-8f);
    }

    // ---- burst-issue ALL E and x chunk loads (16 independent, in flight together) ----
    // unit u -> (row r, segment sg): 87 rows x 22 segs; sg<21 full 4-float, sg==21 = cols 84..86
    float ve[8][4], vx[8][4];
    #pragma unroll
    for (int k = 0; k < 8; ++k) {
        int u = tid + k * NT;
        int uu = (u < 1914) ? u : 0;
        int r = uu / 22, sg = uu - r * 22, c = sg * 4;
        const float* pE = Eb + r * NN + c;
        const float* pX = xb + r * NN + c;
        if (sg < 21) {
            f32x4u te = *(const f32x4u*)pE;
            ve[k][0] = te.x; ve[k][1] = te.y; ve[k][2] = te.z; ve[k][3] = te.w;
            f32x4u tx = *(const f32x4u*)pX;
            vx[k][0] = tx.x; vx[k][1] = tx.y; vx[k][2] = tx.z; vx[k][3] = tx.w;
        } else {
            ve[k][0] = pE[0]; ve[k][1] = pE[1]; ve[k][2] = pE[2]; ve[k][3] = 0.f;
            vx[k][0] = pX[0]; vx[k][1] = pX[1]; vx[k][2] = pX[2]; vx[k][3] = 0.f;
        }
    }

    // ---- zero pads (overlaps load latency): rows 87..95, cols 88..91, tails ----
    {
        const bf16x4 z = {0, 0, 0, 0};
        for (int u = tid; u < 596; u += NT) {
            int p = u & 1, v = u >> 1;
            short* P = p ? sX : sE;
            int off;
            if (v < 207)      { int r = 87 + v / 23, s = v % 23; off = r * PW + s * 4; }
            else if (v < 294) { off = (v - 207) * PW + 88; }
            else              { off = 96 * PW + (v - 294) * 4; }
            *(bf16x4*)&P[off] = z;
        }
    }

    // ---- cvt + write both panels ----
    #pragma unroll
    for (int k = 0; k < 8; ++k) {
        int u = tid + k * NT;
        if (u < 1914) {
            int r = u / 22, sg = u - r * 22, c = sg * 4;
            bf16x4 we = {f2bf(ve[k][0]), f2bf(ve[k][1]), f2bf(ve[k][2]), f2bf(ve[k][3])};
            bf16x4 wx = {f2bf(vx[k][0]), f2bf(vx[k][1]), f2bf(vx[k][2]), f2bf(vx[k][3])};
            *(bf16x4*)&sE[r * PW + c] = we;
            *(bf16x4*)&sX[r * PW + c] = wx;
        }
    }
    __syncthreads();   // B1: panels ready

    // ---------------- GEMM1: D = (E .* exp(-t_i lam_k)) @ E^T ----------------
    f32x4 acc1[3][3];
    #pragma unroll
    for (int c = 0; c < 3; ++c)
        #pragma unroll
        for (int r = 0; r < 3; ++r) acc1[c][r] = (f32x4){0.f, 0.f, 0.f, 0.f};

    #pragma unroll
    for (int ks = 0; ks < 3; ++ks) {
        const int k0 = ks * 32 + lk * 8;
        f32x4 la  = *(const f32x4*)&sLam[k0];
        f32x4 lb4 = *(const f32x4*)&sLam[k0 + 4];
        float l8_[8] = {la.x, la.y, la.z, la.w, lb4.x, lb4.y, lb4.z, lb4.w};

        bf16x8 ef[3], af[3];
        #pragma unroll
        for (int c = 0; c < 3; ++c) {
            bf16x4 lo = *(const bf16x4*)&sE[jr[c] * PW + k0];
            bf16x4 hi = *(const bf16x4*)&sE[jr[c] * PW + k0 + 4];
            #pragma unroll
            for (int q = 0; q < 4; ++q) { ef[c][q] = lo[q]; ef[c][q + 4] = hi[q]; }
        }
        #pragma unroll
        for (int r = 0; r < 3; ++r) {
            bf16x4 lo = *(const bf16x4*)&sE[ir[r] * PW + k0];
            bf16x4 hi = *(const bf16x4*)&sE[ir[r] * PW + k0 + 4];
            #pragma unroll
            for (int q = 0; q < 4; ++q) {
                af[r][q]     = f2bf(bf2f(lo[q]) * __expf(-tr_[r] * l8_[q]));
                af[r][q + 4] = f2bf(bf2f(hi[q]) * __expf(-tr_[r] * l8_[q + 4]));
            }
        }
        #pragma unroll
        for (int c = 0; c < 3; ++c)
            #pragma unroll
            for (int r = 0; r < 3; ++r)
                acc1[c][r] = __builtin_amdgcn_mfma_f32_16x16x32_bf16(ef[c], af[r], acc1[c][r], 0, 0, 0);
    }
    __syncthreads();   // B2: sE reads done -> region reusable for D

    // ---- hoist x-half W fragments (in flight across D-write + B3) ----
    bf16x8 wfx[3][3];
    #pragma unroll
    for (int ks = 0; ks < 3; ++ks)
        #pragma unroll
        for (int wr = 0; wr < 3; ++wr) {
            int jc = jr[wr] < NN ? jr[wr] : NN - 1;
            wfx[ks][wr] = wload<WS>(wpp, gW, 0, jr[wr], jc, ks * 32 + lk * 8, ks == 2);
        }

    // ---- D -> sD (bf16 [96][92]); jb==92 would wrap -> skip ----
    #pragma unroll
    for (int c = 0; c < 3; ++c) {
        const int jb = j0 + 16 * c + lk * 4;
        if (jb < PW) {
            #pragma unroll
            for (int r = 0; r < 3; ++r) {
                const int i = i0 + 16 * r + l15;
                bf16x4 v = {f2bf(acc1[c][r][0]), f2bf(acc1[c][r][1]),
                            f2bf(acc1[c][r][2]), f2bf(acc1[c][r][3])};
                *(bf16x4*)&sD[i * PW + jb] = v;
            }
        }
    }
    __builtin_amdgcn_sched_barrier(0);   // acc1 dead before acc2 is born
    __syncthreads();   // B3: sD visible

    // ---------------- GEMM2: out = x@W1^T + D@W2^T ----------------
    f32x4 acc2[3][3];
    #pragma unroll
    for (int wr = 0; wr < 3; ++wr)
        #pragma unroll
        for (int xc = 0; xc < 3; ++xc) acc2[wr][xc] = (f32x4){0.f, 0.f, 0.f, 0.f};

    #pragma unroll
    for (int ks = 0; ks < 3; ++ks) {
        const int k0 = ks * 32 + lk * 8;
        bf16x8 xf[3];
        #pragma unroll
        for (int xc = 0; xc < 3; ++xc) {
            bf16x4 lo = *(const bf16x4*)&sX[ir[xc] * PW + k0];
            bf16x4 hi = *(const bf16x4*)&sX[ir[xc] * PW + k0 + 4];
            #pragma unroll
            for (int q = 0; q < 4; ++q) { xf[xc][q] = lo[q]; xf[xc][q + 4] = hi[q]; }
        }
        #pragma unroll
        for (int wr = 0; wr < 3; ++wr)
            #pragma unroll
            for (int xc = 0; xc < 3; ++xc)
                acc2[wr][xc] = __builtin_amdgcn_mfma_f32_16x16x32_bf16(wfx[ks][wr], xf[xc], acc2[wr][xc], 0, 0, 0);
    }
    #pragma unroll
    for (int ks = 0; ks < 3; ++ks) {
        const int k0 = ks * 32 + lk * 8;
        bf16x8 wfd[3], df[3];
        #pragma unroll
        for (int wr = 0; wr < 3; ++wr) {
            int jc = jr[wr] < NN ? jr[wr] : NN - 1;
            wfd[wr] = wload<WS>(wpp, gW, 1, jr[wr], jc, k0, ks == 2);
        }
        #pragma unroll
        for (int xc = 0; xc < 3; ++xc) {
            bf16x4 lo = *(const bf16x4*)&sD[ir[xc] * PW + k0];
            bf16x4 hi = *(const bf16x4*)&sD[ir[xc] * PW + k0 + 4];
            #pragma unroll
            for (int q = 0; q < 4; ++q) { df[xc][q] = lo[q]; df[xc][q + 4] = hi[q]; }
        }
        #pragma unroll
        for (int wr = 0; wr < 3; ++wr)
            #pragma unroll
            for (int xc = 0; xc < 3; ++xc)
                acc2[wr][xc] = __builtin_amdgcn_mfma_f32_16x16x32_bf16(wfd[wr], df[xc], acc2[wr][xc], 0, 0, 0);
    }
    __syncthreads();   // B4: sX/sD reads done -> region reusable for sF

    // ---------------- epilogue: pack out tile into sF [96][87] f32 ----------------
    #pragma unroll
    for (int wr = 0; wr < 3; ++wr) {
        const int jb = j0 + 16 * wr + lk * 4;
        float bj[4];
        if (jb + 3 < NN) {
            f32x4u t = *(const f32x4u*)(bias + jb);
            bj[0] = t.x; bj[1] = t.y; bj[2] = t.z; bj[3] = t.w;
        } else {
            #pragma unroll
            for (int q = 0; q < 4; ++q) bj[q] = (jb + q < NN) ? bias[jb + q] : 0.f;
        }
        #pragma unroll
        for (int xc = 0; xc < 3; ++xc) {
            const int i = i0 + 16 * xc + l15;
            #pragma unroll
            for (int q = 0; q < 4; ++q) {
                const int j = jb + q;
                if (j < NN) sF[i * NN + j] = acc2[wr][xc][q] + bj[q];
            }
        }
    }
    __syncthreads();   // B5: sF complete

    // ---------------- copy-out: contiguous, alignment-fixed dwordx4 ----------------
    {
        float* __restrict__ gb = out + (size_t)b * NN2;
        const int s = (4 - ((b * NN2) & 3)) & 3;
        if (tid < s) gb[tid] = sF[tid];
        const int C = (NN2 - s) >> 2;
        for (int m = tid; m < C; m += NT) {
            const int n = s + 4 * m;
            f32x4 v;
            v.x = sF[n]; v.y = sF[n + 1]; v.z = sF[n + 2]; v.w = sF[n + 3];
            *(f32x4*)(gb + n) = v;
        }
        const int tl = s + 4 * C;
        if (tid < NN2 - tl) gb[tl + tid] = sF[tl + tid];
    }
}

extern "C" void kernel_launch(void* const* d_in, const int* in_sizes, int n_in,
                              void* d_out, int out_size, void* d_ws, size_t ws_size,
                              hipStream_t stream)
{
    const float* x     = (const float*)d_in[0];
    const float* evals = (const float*)d_in[1];
    const float* evecs = (const float*)d_in[2];
    const float* dtime = (const float*)d_in[3];
    const float* W     = (const float*)d_in[4];
    const float* bias  = (const float*)d_in[5];
    float* out = (float*)d_out;

    const int B = in_sizes[1] / NN;   // evals is (B, 87)

    if (ws_size >= (size_t)WS_NEED) {
        short* wp = (short*)d_ws;
        prep<<<(2 * WPANEL + NT - 1) / NT, NT, 0, stream>>>(W, wp);
        fused<true><<<dim3(B), dim3(NT), 0, stream>>>(x, evals, evecs, dtime, W, bias, wp, out);
    } else {
        fused<false><<<dim3(B), dim3(NT), 0, stream>>>(x, evals, evecs, dtime, W, bias, nullptr, out);
    }
}

// Round 12
// 93.033 us; speedup vs baseline: 1.0955x; 1.0955x over previous
//
#include <hip/hip_runtime.h>
#include <hip/hip_bf16.h>
#include <math.h>

#define NN    87
#define NN2   (NN * NN)          // 7569
#define EPW   92                 // E panel width (f32) and D/X panel width (bf16)
#define EPN   (96 * EPW + 4)     // 8836 f32 incl 4-elem zero tail
#define WPH   104                // ws W-panel row stride (shorts)
#define WPANEL (96 * WPH)        // 9984 shorts
#define NT    256

// ws layout (bytes)
#define WS_W     0                          // 2 bf16 W panels: 39936 B
#define WS_EPAD  (2 * WPANEL * 2)
#define EPAD_N   8360                       // covers max src idx 95*87+91 = 8356
#define WS_NEED  (WS_EPAD + EPAD_N * 4)     // 73376 B

typedef __attribute__((ext_vector_type(8))) short bf16x8;
typedef __attribute__((ext_vector_type(4))) short bf16x4;
typedef __attribute__((ext_vector_type(4))) float f32x4;
typedef float f32x4u __attribute__((ext_vector_type(4), aligned(4)));

__device__ __forceinline__ short f2bf(float f) {
    __hip_bfloat16 h = __float2bfloat16(f);
    return *(short*)&h;
}

// async global->LDS, 16B per lane; lds dest is wave-uniform base + lane*16 (HW)
__device__ __forceinline__ void gl16(const float* g, float* l) {
    __builtin_amdgcn_global_load_lds(
        (const __attribute__((address_space(1))) void*)g,
        (__attribute__((address_space(3))) void*)l, 16, 0, 0);
}

// W (87x174 fp32) -> two zero-padded bf16 panels [96][104]; plus padded copy of last batch's E
__global__ void prep(const float* __restrict__ W, const float* __restrict__ evecs,
                     int B, char* __restrict__ ws)
{
    int idx = (int)blockIdx.x * NT + (int)threadIdx.x;
    short* wp = (short*)(ws + WS_W);
    float* ep = (float*)(ws + WS_EPAD);
    if (idx < 2 * WPANEL) {
        int p = idx / WPANEL, rem = idx - p * WPANEL;
        int r = rem / WPH, c = rem - r * WPH;
        short v = 0;
        if (r < NN && c < NN) v = f2bf(W[r * (2 * NN) + p * NN + c]);
        wp[idx] = v;
    }
    int i2 = idx - 2 * WPANEL;
    if (i2 >= 0 && i2 < EPAD_N)
        ep[i2] = (i2 < NN2) ? evecs[(size_t)(B - 1) * NN2 + i2] : 0.f;
}

// W fragment: ws bf16 panel (WS) or fp32 W + cvt + k-tail zero (!WS)
template <bool WS>
__device__ __forceinline__ bf16x8 wload(const short* __restrict__ wp,
                                        const float* __restrict__ gW,
                                        int panel, int jrow, int jcl, int k0, bool tailKs)
{
    if constexpr (WS) {
        return *(const bf16x8*)&wp[panel * WPANEL + jrow * WPH + k0];
    } else {
        float v[8];
        if (!tailKs) {
            f32x4u a  = *(const f32x4u*)(gW + jcl * (2 * NN) + panel * NN + k0);
            f32x4u b4 = *(const f32x4u*)(gW + jcl * (2 * NN) + panel * NN + k0 + 4);
            v[0] = a.x; v[1] = a.y; v[2] = a.z; v[3] = a.w;
            v[4] = b4.x; v[5] = b4.y; v[6] = b4.z; v[7] = b4.w;
        } else {
            #pragma unroll
            for (int q = 0; q < 8; ++q) {
                int k = k0 + q;
                v[q] = (k < NN) ? gW[jcl * (2 * NN) + panel * NN + k] : 0.f;
            }
        }
        bf16x8 o;
        #pragma unroll
        for (int q = 0; q < 8; ++q) o[q] = f2bf(v[q]);
        return o;
    }
}

template <bool WS>
__global__ __launch_bounds__(NT, 4)
void fused(const float* __restrict__ gx, const float* __restrict__ gevals,
           const float* __restrict__ gevecs, const float* __restrict__ dtime,
           const float* __restrict__ gW, const float* __restrict__ bias,
           const char* __restrict__ ws, int B, float* __restrict__ out)
{
    // ONE union region (35344 B):
    //   phase 1: sE fp32 [96][92] (DMA dest)
    //   phase 2: sD bf16 [96][92] = shorts [0,8832) | sX bf16 [96][92] = shorts [8832,17664)
    //   phase 3: sF f32 packed [96][87]
    __shared__ __align__(16) float sE[EPN];     // 35344 B
    __shared__ float sLam[96];
    short* const sD = (short*)sE;
    short* const sX = sD + 96 * EPW;            // 8832 shorts in
    float* const sF = (float*)sE;

    const int b    = (int)blockIdx.x;
    const int tid  = (int)threadIdx.x;
    const int lane = tid & 63;
    const int wave = tid >> 6;
    const int l15  = lane & 15;
    const int lk   = lane >> 4;
    const int i0   = (wave >> 1) * 48;
    const int j0   = (wave & 1) * 48;

    const float* __restrict__ Eb = gevecs + (size_t)b * NN2;
    const float* __restrict__ xb = gx     + (size_t)b * NN2;
    const short* wp = nullptr;
    if constexpr (WS) {
        wp = (const short*)(ws + WS_W);
        if (b == B - 1) Eb = (const float*)(ws + WS_EPAD);   // padded, OOB-safe
    }

    // ---- sLam first (its auto-waitcnt drains before any staging is issued) ----
    if (tid < 96) sLam[tid] = (tid < NN) ? gevals[(size_t)b * NN + tid] : 3e38f;

    int ir[3], jr[3];
    float tr_[3];
    #pragma unroll
    for (int r = 0; r < 3; ++r) {
        ir[r] = i0 + 16 * r + l15;
        jr[r] = j0 + 16 * r + l15;
        tr_[r] = fmaxf(dtime[ir[r] < NN ? ir[r] : NN - 1], 1e-8f);
    }

    // ---- sE tail (floats 8832..8835; never DMA'd, read-safe zeros) ----
    if (tid < 4) sE[96 * EPW + tid] = 0.f;

    // ---- stage E ----
    if constexpr (WS) {
        // async DMA: 34 full 1024B chunks + one half chunk; per-lane src = row*87+col remap
        for (int vc = wave; vc < 35; vc += 4) {
            int p   = vc * 256 + lane * 4;
            int row = p / EPW;
            int col = p - row * EPW;
            const float* g = Eb + row * NN + col;
            if (vc < 34) gl16(g, &sE[vc * 256]);
            else if (lane < 32) gl16(g, &sE[vc * 256]);
        }
    } else {
        // reg staging (safe fallback): row segments, explicit pads
        for (int u = tid; u < NN * 22; u += NT) {
            int r = u / 22, sg = u - r * 22, c = sg * 4;
            const float* pE = Eb + r * NN + c;
            if (sg < 21) *(f32x4*)&sE[r * EPW + c] = *(const f32x4u*)pE;
            else { f32x4 t; t.x = pE[0]; t.y = pE[1]; t.z = pE[2]; t.w = 0.f;
                   *(f32x4*)&sE[r * EPW + c] = t; }
        }
        for (int u = tid; u < 96 * 4; u += NT) {                // cols 88..91
            int r = u >> 2, c = 88 + (u & 3);
            sE[r * EPW + c] = 0.f;
        }
        for (int u = tid; u < 9 * 88; u += NT) {                // rows 87..95 cols 0..87
            int r = NN + u / 88, c = u % 88;
            sE[r * EPW + c] = 0.f;
        }
    }

    // ---- issue x loads early (held in regs through GEMM1; written post-B2) ----
    float xq[8][4];
    float x7568 = 0.f;
    #pragma unroll
    for (int k = 0; k < 8; ++k) {
        int u = tid + k * NT;
        int uc = (u < 1892) ? u : 1891;                         // clamp: always in-batch
        f32x4u t = *(const f32x4u*)(xb + 4 * uc);
        xq[k][0] = t.x; xq[k][1] = t.y; xq[k][2] = t.z; xq[k][3] = t.w;
    }
    if (tid == 0) x7568 = xb[7568];

    // ---- B1: E panel ready; x loads stay in flight across the barrier ----
    if constexpr (WS) {
        asm volatile("s_waitcnt vmcnt(8) lgkmcnt(0)" ::: "memory");
        __builtin_amdgcn_s_barrier();
        __builtin_amdgcn_sched_barrier(0);
    } else {
        __syncthreads();
    }

    // ---------------- GEMM1: D = (E .* exp(-t_i lam_k)) @ E^T ----------------
    f32x4 acc1[3][3];
    #pragma unroll
    for (int c = 0; c < 3; ++c)
        #pragma unroll
        for (int r = 0; r < 3; ++r) acc1[c][r] = (f32x4){0.f, 0.f, 0.f, 0.f};

    #pragma unroll
    for (int ks = 0; ks < 3; ++ks) {
        const int k0 = ks * 32 + lk * 8;
        f32x4 la  = *(const f32x4*)&sLam[k0];
        f32x4 lb4 = *(const f32x4*)&sLam[k0 + 4];
        float l8_[8] = {la.x, la.y, la.z, la.w, lb4.x, lb4.y, lb4.z, lb4.w};

        bf16x8 ef[3], af[3];
        #pragma unroll
        for (int c = 0; c < 3; ++c) {
            f32x4 lo = *(const f32x4*)&sE[jr[c] * EPW + k0];
            f32x4 hi = *(const f32x4*)&sE[jr[c] * EPW + k0 + 4];
            #pragma unroll
            for (int q = 0; q < 4; ++q) { ef[c][q] = f2bf(lo[q]); ef[c][q + 4] = f2bf(hi[q]); }
        }
        #pragma unroll
        for (int r = 0; r < 3; ++r) {
            f32x4 lo = *(const f32x4*)&sE[ir[r] * EPW + k0];
            f32x4 hi = *(const f32x4*)&sE[ir[r] * EPW + k0 + 4];
            #pragma unroll
            for (int q = 0; q < 4; ++q) {
                af[r][q]     = f2bf(lo[q] * __expf(-tr_[r] * l8_[q]));
                af[r][q + 4] = f2bf(hi[q] * __expf(-tr_[r] * l8_[q + 4]));
            }
        }
        #pragma unroll
        for (int c = 0; c < 3; ++c)
            #pragma unroll
            for (int r = 0; r < 3; ++r)
                acc1[c][r] = __builtin_amdgcn_mfma_f32_16x16x32_bf16(ef[c], af[r], acc1[c][r], 0, 0, 0);
    }
    __syncthreads();   // B2: all sE reads done -> region reusable for sD | sX

    // ---- D -> sD (bf16 [96][92]); jb==92 would wrap -> skip ----
    #pragma unroll
    for (int c = 0; c < 3; ++c) {
        const int jb = j0 + 16 * c + lk * 4;
        if (jb < EPW) {
            #pragma unroll
            for (int r = 0; r < 3; ++r) {
                const int i = i0 + 16 * r + l15;
                bf16x4 v = {f2bf(acc1[c][r][0]), f2bf(acc1[c][r][1]),
                            f2bf(acc1[c][r][2]), f2bf(acc1[c][r][3])};
                *(bf16x4*)&sD[i * EPW + jb] = v;
            }
        }
    }
    __builtin_amdgcn_sched_barrier(0);     // acc1 dead before acc2 is born

    // ---- write x panel (loads issued pre-B1 have long landed) + sX pads ----
    #pragma unroll
    for (int k = 0; k < 8; ++k) {
        int u = tid + k * NT;
        if (u < 1892) {
            int f = 4 * u;
            #pragma unroll
            for (int e = 0; e < 4; ++e) {
                int fe = f + e;
                if (fe < NN2) {
                    int r = fe / NN, c = fe - r * NN;
                    sX[r * EPW + c] = f2bf(xq[k][e]);
                }
            }
        }
    }
    if (tid == 0) sX[86 * EPW + 86] = f2bf(x7568);
    for (int u = tid; u < 96 * 5; u += NT) {                    // sX cols 87..91
        int r = u / 5, c = NN + u % 5;
        sX[r * EPW + c] = 0;
    }
    for (int u = tid; u < 9 * NN; u += NT) {                    // sX rows 87..95
        int r = NN + u / NN, c = u % NN;
        sX[r * EPW + c] = 0;
    }

    // ---- hoist x-half W fragments only (36 regs; D-half inline to fit 128-reg tier) ----
    bf16x8 wfx[3][3];
    #pragma unroll
    for (int ks = 0; ks < 3; ++ks)
        #pragma unroll
        for (int wr = 0; wr < 3; ++wr) {
            int jc = jr[wr] < NN ? jr[wr] : NN - 1;
            wfx[ks][wr] = wload<WS>(wp, gW, 0, jr[wr], jc, ks * 32 + lk * 8, ks == 2);
        }
    __syncthreads();   // B3: sD + sX visible

    // ---------------- GEMM2: out = x@W1^T + D@W2^T ----------------
    f32x4 acc2[3][3];
    #pragma unroll
    for (int wr = 0; wr < 3; ++wr)
        #pragma unroll
        for (int xc = 0; xc < 3; ++xc) acc2[wr][xc] = (f32x4){0.f, 0.f, 0.f, 0.f};

    #pragma unroll
    for (int ks = 0; ks < 3; ++ks) {
        const int k0 = ks * 32 + lk * 8;
        bf16x8 xf[3];
        #pragma unroll
        for (int xc = 0; xc < 3; ++xc) {
            bf16x4 lo = *(const bf16x4*)&sX[ir[xc] * EPW + k0];
            bf16x4 hi = *(const bf16x4*)&sX[ir[xc] * EPW + k0 + 4];
            #pragma unroll
            for (int q = 0; q < 4; ++q) { xf[xc][q] = lo[q]; xf[xc][q + 4] = hi[q]; }
        }
        #pragma unroll
        for (int wr = 0; wr < 3; ++wr)
            #pragma unroll
            for (int xc = 0; xc < 3; ++xc)
                acc2[wr][xc] = __builtin_amdgcn_mfma_f32_16x16x32_bf16(wfx[ks][wr], xf[xc], acc2[wr][xc], 0, 0, 0);
    }
    #pragma unroll
    for (int ks = 0; ks < 3; ++ks) {
        const int k0 = ks * 32 + lk * 8;
        bf16x8 wfd[3], df[3];
        #pragma unroll
        for (int wr = 0; wr < 3; ++wr) {
            int jc = jr[wr] < NN ? jr[wr] : NN - 1;
            wfd[wr] = wload<WS>(wp, gW, 1, jr[wr], jc, k0, ks == 2);
        }
        #pragma unroll
        for (int xc = 0; xc < 3; ++xc) {
            bf16x4 lo = *(const bf16x4*)&sD[ir[xc] * EPW + k0];
            bf16x4 hi = *(const bf16x4*)&sD[ir[xc] * EPW + k0 + 4];
            #pragma unroll
            for (int q = 0; q < 4; ++q) { df[xc][q] = lo[q]; df[xc][q + 4] = hi[q]; }
        }
        #pragma unroll
        for (int wr = 0; wr < 3; ++wr)
            #pragma unroll
            for (int xc = 0; xc < 3; ++xc)
                acc2[wr][xc] = __builtin_amdgcn_mfma_f32_16x16x32_bf16(wfd[wr], df[xc], acc2[wr][xc], 0, 0, 0);
    }
    __syncthreads();   // B4: sD/sX reads done -> region reusable for sF

    // ---------------- epilogue: pack out tile into sF [96][87] f32 ----------------
    #pragma unroll
    for (int wr = 0; wr < 3; ++wr) {
        const int jb = j0 + 16 * wr + lk * 4;
        float bj[4];
        if (jb + 3 < NN) {
            f32x4u t = *(const f32x4u*)(bias + jb);
            bj[0] = t.x; bj[1] = t.y; bj[2] = t.z; bj[3] = t.w;
        } else {
            #pragma unroll
            for (int q = 0; q < 4; ++q) bj[q] = (jb + q < NN) ? bias[jb + q] : 0.f;
        }
        #pragma unroll
        for (int xc = 0; xc < 3; ++xc) {
            const int i = i0 + 16 * xc + l15;   // rows >=87 land past idx 7569, never copied
            #pragma unroll
            for (int q = 0; q < 4; ++q) {
                const int j = jb + q;
                if (j < NN) sF[i * NN + j] = acc2[wr][xc][q] + bj[q];
            }
        }
    }
    __syncthreads();   // B5: sF complete

    // ---------------- copy-out: contiguous, alignment-fixed dwordx4 ----------------
    {
        float* __restrict__ gb = out + (size_t)b * NN2;
        const int s = (4 - ((b * NN2) & 3)) & 3;
        if (tid < s) gb[tid] = sF[tid];
        const int C = (NN2 - s) >> 2;
        for (int m = tid; m < C; m += NT) {
            const int n = s + 4 * m;
            f32x4 v;
            v.x = sF[n]; v.y = sF[n + 1]; v.z = sF[n + 2]; v.w = sF[n + 3];
            *(f32x4*)(gb + n) = v;
        }
        const int tl = s + 4 * C;
        if (tid < NN2 - tl) gb[tl + tid] = sF[tl + tid];
    }
}

extern "C" void kernel_launch(void* const* d_in, const int* in_sizes, int n_in,
                              void* d_out, int out_size, void* d_ws, size_t ws_size,
                              hipStream_t stream)
{
    const float* x     = (const float*)d_in[0];
    const float* evals = (const float*)d_in[1];
    const float* evecs = (const float*)d_in[2];
    const float* dtime = (const float*)d_in[3];
    const float* W     = (const float*)d_in[4];
    const float* bias  = (const float*)d_in[5];
    float* out = (float*)d_out;

    const int B = in_sizes[1] / NN;   // evals is (B, 87)

    if (ws_size >= (size_t)WS_NEED) {
        const int prep_elems = 2 * WPANEL + EPAD_N;
        prep<<<(prep_elems + NT - 1) / NT, NT, 0, stream>>>(W, evecs, B, (char*)d_ws);
        fused<true><<<dim3(B), dim3(NT), 0, stream>>>(x, evals, evecs, dtime, W, bias,
                                                      (const char*)d_ws, B, out);
    } else {
        fused<false><<<dim3(B), dim3(NT), 0, stream>>>(x, evals, evecs, dtime, W, bias,
                                                       nullptr, B, out);
    }
}